// Round 1
// baseline (351.489 us; speedup 1.0000x reference)
//
#include <hip/hip_runtime.h>
#include <hip/hip_bf16.h>
#include <cstdint>
#include <cstddef>

// Problem constants (fixed by reference)
#define BROWS   16384
#define LDIM    128
#define HDIM    512
#define KDIM    1152            // LABEL_DIM + 2*H_DIM
#define NGATES  2560            // 5 * HDIM  (i, o, u, f0, f1)
#define NKT     (KDIM / 64)     // 18 K-tiles of BK=64

// workspace layout (bytes)
#define XB_BYTES  ((size_t)BROWS * KDIM * 2)            // 37,748,736
#define WB_BYTES  ((size_t)NGATES * KDIM * 2)           //  5,898,240
// gates: BROWS * NGATES bf16 = 83,886,080

using f32x4   = __attribute__((ext_vector_type(4))) float;
using bfrag   = __attribute__((ext_vector_type(8))) short;   // 8 bf16 = 4 VGPRs

__device__ __forceinline__ short f2bf(float f) {
    union { float f; uint32_t u; } a; a.f = f;
    uint32_t u = a.u;
    uint32_t lsb = (u >> 16) & 1u;
    u += 0x7fffu + lsb;               // round-to-nearest-even
    return (short)(u >> 16);
}
__device__ __forceinline__ float bf2f(short s) {
    union { uint32_t u; float f; } a;
    a.u = ((uint32_t)(uint16_t)s) << 16;
    return a.f;
}

__device__ __forceinline__ void load_lds16(const void* g, void* l) {
    __builtin_amdgcn_global_load_lds(
        (const __attribute__((address_space(1))) void*)g,
        (__attribute__((address_space(3))) void*)l, 16, 0, 0);
}

__device__ __forceinline__ float fast_sigmoid(float x) {
    return 1.0f / (1.0f + __expf(-x));
}
__device__ __forceinline__ float fast_tanh(float x) {
    float t = __expf(2.0f * x);
    return 1.0f - 2.0f / (t + 1.0f);
}

// ---------------------------------------------------------------------------
// pack_all: one launch.
//   blocks [0, NBX): xb[b, :] = bf16([label[b,:] | h0[b,:] | h1[b,:]])
//   blocks [NBX, NBX+NBW): Wb row n = bf16 of the gate-n weight row
// 8 elements per thread: 2x float4 load -> 1x 16B bf16 store.
// ---------------------------------------------------------------------------
#define NBX  ((BROWS  * (KDIM / 8)) / 256)   // 9216
#define NBW  ((NGATES * (KDIM / 8)) / 256)   // 1440

__global__ __launch_bounds__(256) void pack_all(
    const float* __restrict__ label, const float* __restrict__ chh,
    const float* __restrict__ Wi, const float* __restrict__ Wo,
    const float* __restrict__ Wu, const float* __restrict__ Wfl,
    const float* __restrict__ Wfs,
    short* __restrict__ xb, short* __restrict__ Wb)
{
    const int perRow = KDIM / 8;  // 144
    int blk = blockIdx.x;
    const float* src;
    short* dst;
    if (blk < NBX) {
        int tid = blk * 256 + threadIdx.x;
        int b = tid / perRow;
        int d = (tid - b * perRow) * 8;
        if (d < LDIM) {
            src = label + (size_t)b * LDIM + d;
        } else {
            int dd = d - LDIM;
            int k  = dd >> 9;
            int j  = dd & 511;
            src = chh + ((size_t)k * BROWS + b) * HDIM + j;
        }
        dst = xb + (size_t)b * KDIM + d;
    } else {
        int tid = (blk - NBX) * 256 + threadIdx.x;
        int n = tid / perRow;
        int d = (tid - n * perRow) * 8;
        int g = n >> 9, h = n & 511;
        if (g == 0)      src = Wi + (size_t)h * KDIM + d;
        else if (g == 1) src = Wo + (size_t)h * KDIM + d;
        else if (g == 2) src = Wu + (size_t)h * KDIM + d;
        else {
            int k = g - 3;
            if (d < LDIM) {
                src = Wfl + (size_t)h * LDIM + d;
            } else {
                int dd = d - LDIM;
                int j  = dd >> 9;
                int jj = dd & 511;
                src = Wfs + (((size_t)(k * 2 + j) * HDIM + h) * HDIM) + jj;
            }
        }
        dst = Wb + (size_t)n * KDIM + d;
    }
    float4 v0 = *(const float4*)src;
    float4 v1 = *(const float4*)(src + 4);
    bfrag s;
    s[0] = f2bf(v0.x); s[1] = f2bf(v0.y); s[2] = f2bf(v0.z); s[3] = f2bf(v0.w);
    s[4] = f2bf(v1.x); s[5] = f2bf(v1.y); s[6] = f2bf(v1.z); s[7] = f2bf(v1.w);
    *(bfrag*)dst = s;
}

// ---------------------------------------------------------------------------
// gemm_bt: 256x256 tile, BK=64, 8 waves (2Mx4N), 8-phase counted-vmcnt
// schedule (T2 swizzle + T3/T4 counted vmcnt + T5 setprio + T1 XCD chunk).
//
// LDS: A,B double-buffered K-tiles, 2 x (256x64) bf16 each = 128 KiB.
// Staging granularity: quarter-tile = 64 rows x 64 cols = 8 KB = 1
// global_load_lds(16B)/thread. XOR swizzle slot^=(row&7) on 128 B rows,
// realized as pre-swizzled GLOBAL source + swizzled ds_read (both-sides
// involution; LDS dest stays lane-linear as global_load_lds requires).
//
// Per K-tile: 4 phases, each = one C-quadrant (4m x 2n frags) x K=64:
//   {12 ds_read_b128 ; prefetch issues} barrier ; lgkmcnt(0) ;
//   setprio(1) 16 MFMA setprio(0) ; barrier
// Prefetch schedule (region legal-issue derived from last-read phase):
//   during tile kt:  ph1: A(kt+1)q1 B(kt+1)q0 B(kt+1)q1   (other buffer)
//                    ph2: A(kt+1)q3 B(kt+1)q2 B(kt+1)q3
//                    ph3: A(kt+2)q0  (same buffer; q0 free after ph2)
//                    ph4: A(kt+2)q2  (free after ph2)
//   boundary: s_waitcnt vmcnt(2)  -> everything for kt+1 landed, the 2
//   newest (A(kt+2)q0/q2) stay in flight. Never vmcnt(0) in steady state.
// ---------------------------------------------------------------------------
__global__ __launch_bounds__(512, 2) void gemm_bt(const short* __restrict__ A,
                                                  const short* __restrict__ Bt,
                                                  short* __restrict__ C) {
    __shared__ short As[2][16384];   // 2 x 32 KB
    __shared__ short Bs[2][16384];   // 2 x 32 KB

    const int t    = threadIdx.x;
    const int lane = t & 63;
    const int wave = t >> 6;          // 0..7
    const int wr   = wave >> 2;       // 0..1  (M)
    const int wc   = wave & 3;        // 0..3  (N)
    const int quad = lane >> 4;       // 0..3
    const int l16  = lane & 15;

    // T1: XCD-aware chunking. 640 blocks, 640%8==0 -> simple bijective map.
    // m-fastest inside a chunk: each XCD keeps one B-panel (590 KB) L2-hot.
    const int swz   = (blockIdx.x & 7) * 80 + (blockIdx.x >> 3);
    const int mBase = (swz & 63) * 256;   // 64 m-tiles
    const int nBase = (swz >> 6) * 256;   // 10 n-tiles

    f32x4 acc[8][4] = {};

    // ---- staging constants (quarter = 64 rows x 128 B; thread t -> row t/8,
    // phys slot t&7, sourced from global slot (t&7)^(row&7)) ----
    const int sr  = t >> 3;               // 0..63
    const int ssl = (t & 7) ^ (sr & 7);   // swizzled 16B slot in row
    const short* aSrc = A  + (size_t)(mBase + sr) * KDIM + ssl * 8;
    const short* bSrc = Bt + (size_t)(nBase + sr) * KDIM + ssl * 8;
    short* aDst = &As[0][0] + t * 8;      // lane-linear LDS dest
    short* bDst = &Bs[0][0] + t * 8;

#define STAGE_A(q, kt, buf) load_lds16(aSrc + (size_t)(q) * (64 * KDIM) + (kt) * 64, \
                                       aDst + (buf) * 16384 + (q) * 4096)
#define STAGE_B(q, kt, buf) load_lds16(bSrc + (size_t)(q) * (64 * KDIM) + (kt) * 64, \
                                       bDst + (buf) * 16384 + (q) * 4096)

    // ---- fragment-read constants (byte offsets). row&7 == l16&7 for all
    // of a thread's fragment rows, so the swizzled k-slot is per-thread const.
    const int kswz0 = ((quad)     ^ (l16 & 7)) << 4;   // ks=0
    const int kswz1 = ((quad + 4) ^ (l16 & 7)) << 4;   // ks=1
    const int aRowB = (wr * 128 + l16) << 7;           // row byte offset in tile
    const int bRowB = (wc * 64  + l16) << 7;

#define DS_A(buf, mh, j, ks) (*(const bfrag*)((const char*)(&As[(buf)][0]) + aRowB + \
                              (mh) * 8192 + (j) * 2048 + ((ks) ? kswz1 : kswz0)))
#define DS_B(buf, nh, j, ks) (*(const bfrag*)((const char*)(&Bs[(buf)][0]) + bRowB + \
                              (nh) * 4096 + (j) * 2048 + ((ks) ? kswz1 : kswz0)))

#define MM(af, bfr, mi, ni) acc[mi][ni] = \
    __builtin_amdgcn_mfma_f32_16x16x32_bf16(af, bfr, acc[mi][ni], 0, 0, 0)

// One phase: quadrant (mh, nh). ds_reads, then prefetch issues (__VA_ARGS__),
// then raw barrier, explicit lgkmcnt drain (memory clobber pins every LDS
// read above it -> safe overwrite after next barrier), prioritized MFMAs.
// Caller supplies the trailing phase barrier (phase 4 inserts vmcnt first).
#define PHASE(buf, mh, nh, ...) do { \
    bfrag a00 = DS_A(buf, mh, 0, 0), a01 = DS_A(buf, mh, 0, 1); \
    bfrag a10 = DS_A(buf, mh, 1, 0), a11 = DS_A(buf, mh, 1, 1); \
    bfrag a20 = DS_A(buf, mh, 2, 0), a21 = DS_A(buf, mh, 2, 1); \
    bfrag a30 = DS_A(buf, mh, 3, 0), a31 = DS_A(buf, mh, 3, 1); \
    bfrag b00 = DS_B(buf, nh, 0, 0), b01 = DS_B(buf, nh, 0, 1); \
    bfrag b10 = DS_B(buf, nh, 1, 0), b11 = DS_B(buf, nh, 1, 1); \
    __VA_ARGS__; \
    __builtin_amdgcn_s_barrier(); \
    asm volatile("s_waitcnt lgkmcnt(0)" ::: "memory"); \
    __builtin_amdgcn_s_setprio(1); \
    MM(a00, b00, (mh)*4+0, (nh)*2+0); \
    MM(a10, b00, (mh)*4+1, (nh)*2+0); \
    MM(a20, b00, (mh)*4+2, (nh)*2+0); \
    MM(a30, b00, (mh)*4+3, (nh)*2+0); \
    MM(a00, b10, (mh)*4+0, (nh)*2+1); \
    MM(a10, b10, (mh)*4+1, (nh)*2+1); \
    MM(a20, b10, (mh)*4+2, (nh)*2+1); \
    MM(a30, b10, (mh)*4+3, (nh)*2+1); \
    MM(a01, b01, (mh)*4+0, (nh)*2+0); \
    MM(a11, b01, (mh)*4+1, (nh)*2+0); \
    MM(a21, b01, (mh)*4+2, (nh)*2+0); \
    MM(a31, b01, (mh)*4+3, (nh)*2+0); \
    MM(a01, b11, (mh)*4+0, (nh)*2+1); \
    MM(a11, b11, (mh)*4+1, (nh)*2+1); \
    MM(a21, b11, (mh)*4+2, (nh)*2+1); \
    MM(a31, b11, (mh)*4+3, (nh)*2+1); \
    __builtin_amdgcn_s_setprio(0); \
} while (0)

    // ---- prologue: K-tile 0 fully + A(1)q0/q2 (2 in flight at first wait)
    STAGE_A(0, 0, 0); STAGE_A(1, 0, 0); STAGE_A(2, 0, 0); STAGE_A(3, 0, 0);
    STAGE_B(0, 0, 0); STAGE_B(1, 0, 0); STAGE_B(2, 0, 0); STAGE_B(3, 0, 0);
    STAGE_A(0, 1, 1); STAGE_A(2, 1, 1);
    asm volatile("s_waitcnt vmcnt(2)" ::: "memory");
    __builtin_amdgcn_s_barrier();

#pragma unroll 1
    for (int k2 = 0; k2 < NKT / 2; ++k2) {
        const int kt   = 2 * k2;
        const bool more = (k2 < NKT / 2 - 1);

        // ---- even K-tile kt (buf 0) ----
        PHASE(0, 0, 0, STAGE_A(1, kt + 1, 1); STAGE_B(0, kt + 1, 1); STAGE_B(1, kt + 1, 1));
        __builtin_amdgcn_s_barrier();
        PHASE(0, 0, 1, STAGE_A(3, kt + 1, 1); STAGE_B(2, kt + 1, 1); STAGE_B(3, kt + 1, 1));
        __builtin_amdgcn_s_barrier();
        PHASE(0, 1, 0, if (more) STAGE_A(0, kt + 2, 0));
        __builtin_amdgcn_s_barrier();
        PHASE(0, 1, 1, if (more) STAGE_A(2, kt + 2, 0));
        if (more) { asm volatile("s_waitcnt vmcnt(2)" ::: "memory"); }
        else      { asm volatile("s_waitcnt vmcnt(0)" ::: "memory"); }
        __builtin_amdgcn_s_barrier();

        // ---- odd K-tile kt+1 (buf 1) ----
        PHASE(1, 0, 0, if (more) { STAGE_A(1, kt + 2, 0); STAGE_B(0, kt + 2, 0); STAGE_B(1, kt + 2, 0); });
        __builtin_amdgcn_s_barrier();
        PHASE(1, 0, 1, if (more) { STAGE_A(3, kt + 2, 0); STAGE_B(2, kt + 2, 0); STAGE_B(3, kt + 2, 0); });
        __builtin_amdgcn_s_barrier();
        PHASE(1, 1, 0, if (more) STAGE_A(0, kt + 3, 1));
        __builtin_amdgcn_s_barrier();
        PHASE(1, 1, 1, if (more) STAGE_A(2, kt + 3, 1));
        if (more) { asm volatile("s_waitcnt vmcnt(2)" ::: "memory"); }
        else      { asm volatile("s_waitcnt vmcnt(0)" ::: "memory"); }
        __builtin_amdgcn_s_barrier();
    }

    // ---- epilogue: C[m,n] bf16; C/D layout col=lane&15, row=(lane>>4)*4+r
#pragma unroll
    for (int mi = 0; mi < 8; ++mi) {
        const int row0 = mBase + wr * 128 + mi * 16 + quad * 4;
#pragma unroll
        for (int ni = 0; ni < 4; ++ni) {
            const int col = nBase + wc * 64 + ni * 16 + l16;
#pragma unroll
            for (int r = 0; r < 4; ++r) {
                C[(size_t)(row0 + r) * NGATES + col] = f2bf(acc[mi][ni][r]);
            }
        }
    }
#undef PHASE
#undef MM
#undef DS_A
#undef DS_B
#undef STAGE_A
#undef STAGE_B
}

// ---------------------------------------------------------------------------
// epilogue: gates (B x 2560 bf16 logits) -> next_cell, out (fp32).
// 8 h-columns per thread: each gate read is one 16B bfrag, chc/out via float4.
// ---------------------------------------------------------------------------
__global__ __launch_bounds__(256) void epilogue(const short* __restrict__ gates,
                                                const float* __restrict__ chc,
                                                const float* __restrict__ b_i,
                                                const float* __restrict__ b_o,
                                                const float* __restrict__ b_u,
                                                const float* __restrict__ fbias,
                                                float* __restrict__ out) {
    int tid = blockIdx.x * 256 + threadIdx.x;     // over B * (H/8)
    int b  = tid >> 6;                            // H/8 = 64 per row
    int h8 = (tid & 63) << 3;

    const short* g = gates + (size_t)b * NGATES + h8;
    bfrag vi  = *(const bfrag*)(g);
    bfrag vo  = *(const bfrag*)(g + HDIM);
    bfrag vu  = *(const bfrag*)(g + 2 * HDIM);
    bfrag vf0 = *(const bfrag*)(g + 3 * HDIM);
    bfrag vf1 = *(const bfrag*)(g + 4 * HDIM);

    float4 bi0 = *(const float4*)(b_i + h8),   bi1 = *(const float4*)(b_i + h8 + 4);
    float4 bo0 = *(const float4*)(b_o + h8),   bo1 = *(const float4*)(b_o + h8 + 4);
    float4 bu0 = *(const float4*)(b_u + h8),   bu1 = *(const float4*)(b_u + h8 + 4);
    float4 fb0 = *(const float4*)(fbias + h8), fb1 = *(const float4*)(fbias + h8 + 4);

    size_t cbase = (size_t)b * HDIM + h8;
    float4 c00 = *(const float4*)(chc + cbase);
    float4 c01 = *(const float4*)(chc + cbase + 4);
    float4 c10 = *(const float4*)(chc + (size_t)BROWS * HDIM + cbase);
    float4 c11 = *(const float4*)(chc + (size_t)BROWS * HDIM + cbase + 4);

    float bi[8] = {bi0.x,bi0.y,bi0.z,bi0.w, bi1.x,bi1.y,bi1.z,bi1.w};
    float bo[8] = {bo0.x,bo0.y,bo0.z,bo0.w, bo1.x,bo1.y,bo1.z,bo1.w};
    float bu[8] = {bu0.x,bu0.y,bu0.z,bu0.w, bu1.x,bu1.y,bu1.z,bu1.w};
    float fb[8] = {fb0.x,fb0.y,fb0.z,fb0.w, fb1.x,fb1.y,fb1.z,fb1.w};
    float c0[8] = {c00.x,c00.y,c00.z,c00.w, c01.x,c01.y,c01.z,c01.w};
    float c1[8] = {c10.x,c10.y,c10.z,c10.w, c11.x,c11.y,c11.z,c11.w};

    float nc[8], ou[8];
#pragma unroll
    for (int e = 0; e < 8; ++e) {
        float ig = fast_sigmoid(bf2f(vi[e]) + bi[e]);
        float og = fast_sigmoid(bf2f(vo[e]) + bo[e]);
        float uu = fast_tanh(bf2f(vu[e]) + bu[e]);
        float f0 = fast_sigmoid(bf2f(vf0[e]));
        float f1 = fast_sigmoid(bf2f(vf1[e]));
        float ncell = ig * uu + f0 * c0[e] + f1 * c1[e] + fb[e] * (c0[e] + c1[e]);
        nc[e] = ncell;
        ou[e] = fast_tanh(og * ncell);
    }
    float4 n0 = {nc[0], nc[1], nc[2], nc[3]}, n1 = {nc[4], nc[5], nc[6], nc[7]};
    float4 o0 = {ou[0], ou[1], ou[2], ou[3]}, o1 = {ou[4], ou[5], ou[6], ou[7]};
    *(float4*)(out + cbase)     = n0;
    *(float4*)(out + cbase + 4) = n1;
    *(float4*)(out + (size_t)BROWS * HDIM + cbase)     = o0;
    *(float4*)(out + (size_t)BROWS * HDIM + cbase + 4) = o1;
}

// ---------------------------------------------------------------------------
extern "C" void kernel_launch(void* const* d_in, const int* in_sizes, int n_in,
                              void* d_out, int out_size, void* d_ws, size_t ws_size,
                              hipStream_t stream) {
    const float* label = (const float*)d_in[0];
    const float* chh   = (const float*)d_in[1];
    const float* chc   = (const float*)d_in[2];
    const float* W_i   = (const float*)d_in[3];
    const float* b_i   = (const float*)d_in[4];
    const float* W_o   = (const float*)d_in[5];
    const float* b_o   = (const float*)d_in[6];
    const float* W_u   = (const float*)d_in[7];
    const float* b_u   = (const float*)d_in[8];
    const float* W_fl  = (const float*)d_in[9];
    const float* W_fs  = (const float*)d_in[10];
    const float* fbias = (const float*)d_in[11];
    float* out = (float*)d_out;

    char* ws = (char*)d_ws;
    short* xb    = (short*)ws;                          // B x K bf16
    short* Wb    = (short*)(ws + XB_BYTES);             // 2560 x K bf16
    short* gates = (short*)(ws + XB_BYTES + WB_BYTES);  // B x 2560 bf16

    pack_all<<<NBX + NBW, 256, 0, stream>>>(label, chh, W_i, W_o, W_u, W_fl, W_fs, xb, Wb);

    // 256x256 tiles: (16384/256) x (2560/256) = 64 x 10 = 640 blocks, 512 thr
    gemm_bt<<<dim3(640), 512, 0, stream>>>(xb, Wb, gates);

    epilogue<<<(BROWS * (HDIM / 8)) / 256, 256, 0, stream>>>(gates, chc, b_i, b_o, b_u, fbias, out);
}

// Round 2
// 332.174 us; speedup vs baseline: 1.0581x; 1.0581x over previous
//
#include <hip/hip_runtime.h>
#include <hip/hip_bf16.h>
#include <cstdint>
#include <cstddef>

// Problem constants (fixed by reference)
#define BROWS   16384
#define LDIM    128
#define HDIM    512
#define KDIM    1152            // LABEL_DIM + 2*H_DIM
#define NGATES  2560            // 5 * HDIM  (i, o, u, f0, f1)
#define NKT     (KDIM / 64)     // 18 K-tiles of BK=64

// workspace layout (bytes)
#define XB_BYTES  ((size_t)BROWS * KDIM * 2)            // 37,748,736
#define WB_BYTES  ((size_t)NGATES * KDIM * 2)           //  5,898,240
// gates: BROWS * NGATES bf16 = 83,886,080

using f32x4   = __attribute__((ext_vector_type(4))) float;
using bfrag   = __attribute__((ext_vector_type(8))) short;   // 8 bf16 = 4 VGPRs

__device__ __forceinline__ short f2bf(float f) {
    union { float f; uint32_t u; } a; a.f = f;
    uint32_t u = a.u;
    uint32_t lsb = (u >> 16) & 1u;
    u += 0x7fffu + lsb;               // round-to-nearest-even
    return (short)(u >> 16);
}
__device__ __forceinline__ float bf2f(short s) {
    union { uint32_t u; float f; } a;
    a.u = ((uint32_t)(uint16_t)s) << 16;
    return a.f;
}

__device__ __forceinline__ void load_lds16(const void* g, void* l) {
    __builtin_amdgcn_global_load_lds(
        (const __attribute__((address_space(1))) void*)g,
        (__attribute__((address_space(3))) void*)l, 16, 0, 0);
}

__device__ __forceinline__ float fast_sigmoid(float x) {
    return 1.0f / (1.0f + __expf(-x));
}
__device__ __forceinline__ float fast_tanh(float x) {
    float t = __expf(2.0f * x);
    return 1.0f - 2.0f / (t + 1.0f);
}

// ---------------------------------------------------------------------------
// pack_all: one launch.
//   blocks [0, NBX): xb[b, :] = bf16([label[b,:] | h0[b,:] | h1[b,:]])
//   blocks [NBX, NBX+NBW): Wb row n = bf16 of the gate-n weight row
// 8 elements per thread: 2x float4 load -> 1x 16B bf16 store.
// ---------------------------------------------------------------------------
#define NBX  ((BROWS  * (KDIM / 8)) / 256)   // 9216
#define NBW  ((NGATES * (KDIM / 8)) / 256)   // 1440

__global__ __launch_bounds__(256) void pack_all(
    const float* __restrict__ label, const float* __restrict__ chh,
    const float* __restrict__ Wi, const float* __restrict__ Wo,
    const float* __restrict__ Wu, const float* __restrict__ Wfl,
    const float* __restrict__ Wfs,
    short* __restrict__ xb, short* __restrict__ Wb)
{
    const int perRow = KDIM / 8;  // 144
    int blk = blockIdx.x;
    const float* src;
    short* dst;
    if (blk < NBX) {
        int tid = blk * 256 + threadIdx.x;
        int b = tid / perRow;
        int d = (tid - b * perRow) * 8;
        if (d < LDIM) {
            src = label + (size_t)b * LDIM + d;
        } else {
            int dd = d - LDIM;
            int k  = dd >> 9;
            int j  = dd & 511;
            src = chh + ((size_t)k * BROWS + b) * HDIM + j;
        }
        dst = xb + (size_t)b * KDIM + d;
    } else {
        int tid = (blk - NBX) * 256 + threadIdx.x;
        int n = tid / perRow;
        int d = (tid - n * perRow) * 8;
        int g = n >> 9, h = n & 511;
        if (g == 0)      src = Wi + (size_t)h * KDIM + d;
        else if (g == 1) src = Wo + (size_t)h * KDIM + d;
        else if (g == 2) src = Wu + (size_t)h * KDIM + d;
        else {
            int k = g - 3;
            if (d < LDIM) {
                src = Wfl + (size_t)h * LDIM + d;
            } else {
                int dd = d - LDIM;
                int j  = dd >> 9;
                int jj = dd & 511;
                src = Wfs + (((size_t)(k * 2 + j) * HDIM + h) * HDIM) + jj;
            }
        }
        dst = Wb + (size_t)n * KDIM + d;
    }
    float4 v0 = *(const float4*)src;
    float4 v1 = *(const float4*)(src + 4);
    bfrag s;
    s[0] = f2bf(v0.x); s[1] = f2bf(v0.y); s[2] = f2bf(v0.z); s[3] = f2bf(v0.w);
    s[4] = f2bf(v1.x); s[5] = f2bf(v1.y); s[6] = f2bf(v1.z); s[7] = f2bf(v1.w);
    *(bfrag*)dst = s;
}

// ---------------------------------------------------------------------------
// gemm_bt: 256x256 tile, BK=64, 8 waves (2Mx4N), 4-phase counted-vmcnt
// schedule. Round-1 lesson: two barriers + lgkmcnt(0) per phase lockstep the
// LDS and MFMA pipes (measured 26% MfmaUtil). This version:
//  * ONE trailing barrier per phase, no explicit lgkm drain — compiler emits
//    fine-grained lgkmcnt(N) between ds_read and MFMA, so reads of late waves
//    overlap MFMAs of early waves.
//  * Phases split (mh, ks) instead of (mh, nh): 8 ds_read_b128 + 16 MFMA per
//    phase (A-frags no longer read twice per K-tile). Per-CU per phase:
//    LDS ~640 cyc vs MFMA ~621 cyc — MFMA-bound.
//  * n-fastest XCD chunking: XCD c owns m-tiles [8c,8c+8) x all n. The ~32
//    concurrent blocks per XCD share ~4 A-panels (2.4 MB, L2-resident)
//    instead of streaming 32 distinct panels from L3.
// WAR safety of stage-DMAs (one-barrier version): a phase's reads complete
// before its own MFMAs (compiler waitcnt), which precede its trailing
// barrier; every STAGE below is issued >= 1 trailing barrier after its
// target quarter's last read. Quarter last-read map per tile (buf b):
//   A q0/q2: phases (0,0),(0,1)   -> free after phase 2's barrier
//   A q1/q3: phases (1,0),(1,1)   -> free after tile-end barrier
//   B q0-q3: every phase          -> free after tile-end barrier
// Prefetch schedule (identical counts to round 1, legality re-derived):
//   tile kt:  ph(0,0): A(kt+1)q1 B(kt+1)q0 B(kt+1)q1   (other buffer)
//             ph(0,1): A(kt+1)q3 B(kt+1)q2 B(kt+1)q3
//             ph(1,0): A(kt+2)q0  (same buffer; q0 free after ph2)
//             ph(1,1): A(kt+2)q2
//   boundary: s_waitcnt vmcnt(2) -> kt+1 fully landed, the 2 newest
//   (A(kt+2)q0/q2) stay in flight. Never vmcnt(0) in steady state.
// ---------------------------------------------------------------------------
__global__ __launch_bounds__(512, 2) void gemm_bt(const short* __restrict__ A,
                                                  const short* __restrict__ Bt,
                                                  short* __restrict__ C) {
    __shared__ short As[2][16384];   // 2 x 32 KB
    __shared__ short Bs[2][16384];   // 2 x 32 KB

    const int t    = threadIdx.x;
    const int lane = t & 63;
    const int wave = t >> 6;          // 0..7
    const int wr   = wave >> 2;       // 0..1  (M)
    const int wc   = wave & 3;        // 0..3  (N)
    const int quad = lane >> 4;       // 0..3
    const int l16  = lane & 15;

    // T1 (n-fastest): XCD c = bid&7 gets m-tiles [8c, 8c+8) x all 10 n-tiles,
    // n fastest. Concurrent 32 blocks/XCD share ~4 A-panels (L2-hot) + all B.
    const int local = blockIdx.x >> 3;           // 0..79
    const int mT    = (blockIdx.x & 7) * 8 + local / 10;
    const int nT    = local % 10;
    const int mBase = mT * 256;
    const int nBase = nT * 256;

    f32x4 acc[8][4] = {};

    // ---- staging constants (quarter = 64 rows x 128 B; thread t -> row t/8,
    // phys slot t&7, sourced from global slot (t&7)^(row&7)) ----
    const int sr  = t >> 3;               // 0..63
    const int ssl = (t & 7) ^ (sr & 7);   // swizzled 16B slot in row
    const short* aSrc = A  + (size_t)(mBase + sr) * KDIM + ssl * 8;
    const short* bSrc = Bt + (size_t)(nBase + sr) * KDIM + ssl * 8;
    short* aDst = &As[0][0] + t * 8;      // lane-linear LDS dest
    short* bDst = &Bs[0][0] + t * 8;

#define STAGE_A(q, kt, buf) load_lds16(aSrc + (size_t)(q) * (64 * KDIM) + (kt) * 64, \
                                       aDst + (buf) * 16384 + (q) * 4096)
#define STAGE_B(q, kt, buf) load_lds16(bSrc + (size_t)(q) * (64 * KDIM) + (kt) * 64, \
                                       bDst + (buf) * 16384 + (q) * 4096)

    // ---- fragment-read constants (byte offsets). row&7 == l16&7 for all
    // of a thread's fragment rows, so the swizzled k-slot is per-thread const.
    const int kswz0 = ((quad)     ^ (l16 & 7)) << 4;   // ks=0
    const int kswz1 = ((quad + 4) ^ (l16 & 7)) << 4;   // ks=1
    const int aRowB = (wr * 128 + l16) << 7;           // row byte offset in tile
    const int bRowB = (wc * 64  + l16) << 7;

    // A frag (mh-group, i in 0..3): rows wr*128 + mh*64 + i*16 + l16
#define DS_A(buf, mh, i, ks) (*(const bfrag*)((const char*)(&As[(buf)][0]) + aRowB + \
                              (mh) * 8192 + (i) * 2048 + ((ks) ? kswz1 : kswz0)))
    // B frag (j in 0..3): rows wc*64 + j*16 + l16
#define DS_B(buf, j, ks) (*(const bfrag*)((const char*)(&Bs[(buf)][0]) + bRowB + \
                              (j) * 2048 + ((ks) ? kswz1 : kswz0)))

#define MM(af, bfr, mi, ni) acc[mi][ni] = \
    __builtin_amdgcn_mfma_f32_16x16x32_bf16(af, bfr, acc[mi][ni], 0, 0, 0)

// One phase: (mh, ks). 8 ds_read_b128, prefetch issues, 16 MFMA. No leading
// barrier, no lgkm drain — compiler's per-use lgkmcnt(N) pipelines reads
// under MFMAs; the caller appends the single trailing barrier (boundary
// phases prepend a counted vmcnt).
#define PHASE(buf, mh, ks, ...) do { \
    bfrag a0 = DS_A(buf, mh, 0, ks); \
    bfrag a1 = DS_A(buf, mh, 1, ks); \
    bfrag a2 = DS_A(buf, mh, 2, ks); \
    bfrag a3 = DS_A(buf, mh, 3, ks); \
    bfrag b0 = DS_B(buf, 0, ks); \
    bfrag b1 = DS_B(buf, 1, ks); \
    bfrag b2 = DS_B(buf, 2, ks); \
    bfrag b3 = DS_B(buf, 3, ks); \
    __VA_ARGS__; \
    __builtin_amdgcn_s_setprio(1); \
    MM(a0, b0, (mh)*4+0, 0); MM(a0, b1, (mh)*4+0, 1); \
    MM(a0, b2, (mh)*4+0, 2); MM(a0, b3, (mh)*4+0, 3); \
    MM(a1, b0, (mh)*4+1, 0); MM(a1, b1, (mh)*4+1, 1); \
    MM(a1, b2, (mh)*4+1, 2); MM(a1, b3, (mh)*4+1, 3); \
    MM(a2, b0, (mh)*4+2, 0); MM(a2, b1, (mh)*4+2, 1); \
    MM(a2, b2, (mh)*4+2, 2); MM(a2, b3, (mh)*4+2, 3); \
    MM(a3, b0, (mh)*4+3, 0); MM(a3, b1, (mh)*4+3, 1); \
    MM(a3, b2, (mh)*4+3, 2); MM(a3, b3, (mh)*4+3, 3); \
    __builtin_amdgcn_s_setprio(0); \
} while (0)

    // ---- prologue: K-tile 0 fully + A(1)q0/q2 (2 in flight at first wait)
    STAGE_A(0, 0, 0); STAGE_A(1, 0, 0); STAGE_A(2, 0, 0); STAGE_A(3, 0, 0);
    STAGE_B(0, 0, 0); STAGE_B(1, 0, 0); STAGE_B(2, 0, 0); STAGE_B(3, 0, 0);
    STAGE_A(0, 1, 1); STAGE_A(2, 1, 1);
    asm volatile("s_waitcnt vmcnt(2)" ::: "memory");
    __builtin_amdgcn_s_barrier();

#pragma unroll 1
    for (int k2 = 0; k2 < NKT / 2; ++k2) {
        const int kt   = 2 * k2;
        const bool more = (k2 < NKT / 2 - 1);

        // ---- even K-tile kt (buf 0) ----
        PHASE(0, 0, 0, STAGE_A(1, kt + 1, 1); STAGE_B(0, kt + 1, 1); STAGE_B(1, kt + 1, 1));
        __builtin_amdgcn_s_barrier();
        PHASE(0, 0, 1, STAGE_A(3, kt + 1, 1); STAGE_B(2, kt + 1, 1); STAGE_B(3, kt + 1, 1));
        __builtin_amdgcn_s_barrier();
        PHASE(0, 1, 0, if (more) STAGE_A(0, kt + 2, 0));
        __builtin_amdgcn_s_barrier();
        PHASE(0, 1, 1, if (more) STAGE_A(2, kt + 2, 0));
        if (more) { asm volatile("s_waitcnt vmcnt(2)" ::: "memory"); }
        else      { asm volatile("s_waitcnt vmcnt(0)" ::: "memory"); }
        __builtin_amdgcn_s_barrier();

        // ---- odd K-tile kt+1 (buf 1) ----
        PHASE(1, 0, 0, if (more) { STAGE_A(1, kt + 2, 0); STAGE_B(0, kt + 2, 0); STAGE_B(1, kt + 2, 0); });
        __builtin_amdgcn_s_barrier();
        PHASE(1, 0, 1, if (more) { STAGE_A(3, kt + 2, 0); STAGE_B(2, kt + 2, 0); STAGE_B(3, kt + 2, 0); });
        __builtin_amdgcn_s_barrier();
        PHASE(1, 1, 0, if (more) STAGE_A(0, kt + 3, 1));
        __builtin_amdgcn_s_barrier();
        PHASE(1, 1, 1, if (more) STAGE_A(2, kt + 3, 1));
        if (more) { asm volatile("s_waitcnt vmcnt(2)" ::: "memory"); }
        else      { asm volatile("s_waitcnt vmcnt(0)" ::: "memory"); }
        __builtin_amdgcn_s_barrier();
    }

    // ---- epilogue: C[m,n] bf16; C/D layout col=lane&15, row=(lane>>4)*4+r
#pragma unroll
    for (int mi = 0; mi < 8; ++mi) {
        const int row0 = mBase + wr * 128 + mi * 16 + quad * 4;
#pragma unroll
        for (int ni = 0; ni < 4; ++ni) {
            const int col = nBase + wc * 64 + ni * 16 + l16;
#pragma unroll
            for (int r = 0; r < 4; ++r) {
                C[(size_t)(row0 + r) * NGATES + col] = f2bf(acc[mi][ni][r]);
            }
        }
    }
#undef PHASE
#undef MM
#undef DS_A
#undef DS_B
#undef STAGE_A
#undef STAGE_B
}

// ---------------------------------------------------------------------------
// epilogue: gates (B x 2560 bf16 logits) -> next_cell, out (fp32).
// 8 h-columns per thread: each gate read is one 16B bfrag, chc/out via float4.
// ---------------------------------------------------------------------------
__global__ __launch_bounds__(256) void epilogue(const short* __restrict__ gates,
                                                const float* __restrict__ chc,
                                                const float* __restrict__ b_i,
                                                const float* __restrict__ b_o,
                                                const float* __restrict__ b_u,
                                                const float* __restrict__ fbias,
                                                float* __restrict__ out) {
    int tid = blockIdx.x * 256 + threadIdx.x;     // over B * (H/8)
    int b  = tid >> 6;                            // H/8 = 64 per row
    int h8 = (tid & 63) << 3;

    const short* g = gates + (size_t)b * NGATES + h8;
    bfrag vi  = *(const bfrag*)(g);
    bfrag vo  = *(const bfrag*)(g + HDIM);
    bfrag vu  = *(const bfrag*)(g + 2 * HDIM);
    bfrag vf0 = *(const bfrag*)(g + 3 * HDIM);
    bfrag vf1 = *(const bfrag*)(g + 4 * HDIM);

    float4 bi0 = *(const float4*)(b_i + h8),   bi1 = *(const float4*)(b_i + h8 + 4);
    float4 bo0 = *(const float4*)(b_o + h8),   bo1 = *(const float4*)(b_o + h8 + 4);
    float4 bu0 = *(const float4*)(b_u + h8),   bu1 = *(const float4*)(b_u + h8 + 4);
    float4 fb0 = *(const float4*)(fbias + h8), fb1 = *(const float4*)(fbias + h8 + 4);

    size_t cbase = (size_t)b * HDIM + h8;
    float4 c00 = *(const float4*)(chc + cbase);
    float4 c01 = *(const float4*)(chc + cbase + 4);
    float4 c10 = *(const float4*)(chc + (size_t)BROWS * HDIM + cbase);
    float4 c11 = *(const float4*)(chc + (size_t)BROWS * HDIM + cbase + 4);

    float bi[8] = {bi0.x,bi0.y,bi0.z,bi0.w, bi1.x,bi1.y,bi1.z,bi1.w};
    float bo[8] = {bo0.x,bo0.y,bo0.z,bo0.w, bo1.x,bo1.y,bo1.z,bo1.w};
    float bu[8] = {bu0.x,bu0.y,bu0.z,bu0.w, bu1.x,bu1.y,bu1.z,bu1.w};
    float fb[8] = {fb0.x,fb0.y,fb0.z,fb0.w, fb1.x,fb1.y,fb1.z,fb1.w};
    float c0[8] = {c00.x,c00.y,c00.z,c00.w, c01.x,c01.y,c01.z,c01.w};
    float c1[8] = {c10.x,c10.y,c10.z,c10.w, c11.x,c11.y,c11.z,c11.w};

    float nc[8], ou[8];
#pragma unroll
    for (int e = 0; e < 8; ++e) {
        float ig = fast_sigmoid(bf2f(vi[e]) + bi[e]);
        float og = fast_sigmoid(bf2f(vo[e]) + bo[e]);
        float uu = fast_tanh(bf2f(vu[e]) + bu[e]);
        float f0 = fast_sigmoid(bf2f(vf0[e]));
        float f1 = fast_sigmoid(bf2f(vf1[e]));
        float ncell = ig * uu + f0 * c0[e] + f1 * c1[e] + fb[e] * (c0[e] + c1[e]);
        nc[e] = ncell;
        ou[e] = fast_tanh(og * ncell);
    }
    float4 n0 = {nc[0], nc[1], nc[2], nc[3]}, n1 = {nc[4], nc[5], nc[6], nc[7]};
    float4 o0 = {ou[0], ou[1], ou[2], ou[3]}, o1 = {ou[4], ou[5], ou[6], ou[7]};
    *(float4*)(out + cbase)     = n0;
    *(float4*)(out + cbase + 4) = n1;
    *(float4*)(out + (size_t)BROWS * HDIM + cbase)     = o0;
    *(float4*)(out + (size_t)BROWS * HDIM + cbase + 4) = o1;
}

// ---------------------------------------------------------------------------
extern "C" void kernel_launch(void* const* d_in, const int* in_sizes, int n_in,
                              void* d_out, int out_size, void* d_ws, size_t ws_size,
                              hipStream_t stream) {
    const float* label = (const float*)d_in[0];
    const float* chh   = (const float*)d_in[1];
    const float* chc   = (const float*)d_in[2];
    const float* W_i   = (const float*)d_in[3];
    const float* b_i   = (const float*)d_in[4];
    const float* W_o   = (const float*)d_in[5];
    const float* b_o   = (const float*)d_in[6];
    const float* W_u   = (const float*)d_in[7];
    const float* b_u   = (const float*)d_in[8];
    const float* W_fl  = (const float*)d_in[9];
    const float* W_fs  = (const float*)d_in[10];
    const float* fbias = (const float*)d_in[11];
    float* out = (float*)d_out;

    char* ws = (char*)d_ws;
    short* xb    = (short*)ws;                          // B x K bf16
    short* Wb    = (short*)(ws + XB_BYTES);             // 2560 x K bf16
    short* gates = (short*)(ws + XB_BYTES + WB_BYTES);  // B x 2560 bf16

    pack_all<<<NBX + NBW, 256, 0, stream>>>(label, chh, W_i, W_o, W_u, W_fl, W_fs, xb, Wb);

    // 256x256 tiles: (16384/256) x (2560/256) = 64 x 10 = 640 blocks, 512 thr
    gemm_bt<<<dim3(640), 512, 0, stream>>>(xb, Wb, gates);

    epilogue<<<(BROWS * (HDIM / 8)) / 256, 256, 0, stream>>>(gates, chc, b_i, b_o, b_u, fbias, out);
}